// Round 5
// baseline (4086.014 us; speedup 1.0000x reference)
//
#include <hip/hip_runtime.h>
#include <hip/hip_fp16.h>

#define B_  64
#define T_  2048
#define I_  64
#define H_  256
#define G4_ 1024   // 4*H

typedef _Float16 h2v __attribute__((ext_vector_type(2)));

__device__ __forceinline__ float fdot2(uint32_t a, uint32_t b, float c) {
#if __has_builtin(__builtin_amdgcn_fdot2)
    return __builtin_amdgcn_fdot2(__builtin_bit_cast(h2v, a), __builtin_bit_cast(h2v, b), c, false);
#else
    h2v ha = __builtin_bit_cast(h2v, a), hb = __builtin_bit_cast(h2v, b);
    return c + (float)ha.x * (float)hb.x + (float)ha.y * (float)hb.y;
#endif
}

__device__ __forceinline__ ushort f2h(float v) {
    return __builtin_bit_cast(ushort, (_Float16)v);
}
__device__ __forceinline__ float h2f(ushort v) {
    return (float)__builtin_bit_cast(_Float16, v);
}

// ---------------------------------------------------------------------------
// Repack W_hh fp32 [1024][256] -> f16 wpk[g][kc][h][j]  (g=gate, kc=K/8 chunk,
// h=hdim 0..255, j=0..7).  Coalesced 16B/lane preload in the LSTM kernel.
// ---------------------------------------------------------------------------
__global__ void repack_kernel(const float* __restrict__ Whh, ushort* __restrict__ wpk) {
    int o  = blockIdx.x * 256 + threadIdx.x;   // 0 .. 262143
    int j  = o & 7;
    int h  = (o >> 3) & 255;
    int kc = (o >> 11) & 31;
    int g  = o >> 16;
    float v = Whh[(g * 256 + h) * 256 + kc * 8 + j];
    wpk[o] = f2h(v);
}

// ---------------------------------------------------------------------------
// gx2 = x @ W_ih^T + b_ih + b_hh, TRANSPOSED f16 layout [bt][hd][gate] so the
// lstm kernel fetches one ushort4 per (t,hd).  grid = ((64*TCc)/32, 4).
// Stores are 2B stride-8B scattered; the 4 gate-blocks interleave and L2
// write-combines before HBM eviction.
// ---------------------------------------------------------------------------
__global__ __launch_bounds__(256) void gx_kernel(
    const float* __restrict__ x, const float* __restrict__ Wih,
    const float* __restrict__ bih, const float* __restrict__ bhh,
    ushort* __restrict__ gx2, int t0, int TCc) {

    __shared__ float xs[32][64];
    const int bt0 = blockIdx.x * 32;
    const int gq  = blockIdx.y;                 // gate quarter 0..3
    const int row = gq * 256 + threadIdx.x;     // W_ih row

    // vectorized x tile load: 512 float4
    for (int i = threadIdx.x; i < 512; i += 256) {
        int r  = i >> 4, c4 = i & 15;
        int bt = bt0 + r;
        int b  = bt / TCc;
        int tl = bt - b * TCc;
        *(float4*)(&xs[r][c4 * 4]) =
            *(const float4*)(&x[(((size_t)b * T_) + t0 + tl) * I_ + c4 * 4]);
    }
    __syncthreads();

    float w[64];
#pragma unroll
    for (int k = 0; k < 64; ++k) w[k] = Wih[row * I_ + k];
    const float bias = bih[row] + bhh[row];

    for (int i = 0; i < 32; ++i) {
        float acc = bias;
#pragma unroll
        for (int k4 = 0; k4 < 16; ++k4) {
            float4 xq = *(const float4*)(&xs[i][k4 * 4]);
            acc = fmaf(w[k4 * 4 + 0], xq.x, acc);
            acc = fmaf(w[k4 * 4 + 1], xq.y, acc);
            acc = fmaf(w[k4 * 4 + 2], xq.z, acc);
            acc = fmaf(w[k4 * 4 + 3], xq.w, acc);
        }
        gx2[((size_t)(bt0 + i) * 256 + threadIdx.x) * 4 + gq] = f2h(acc);
    }
}

// ---------------------------------------------------------------------------
// Persistent per-batch LSTM.  64 blocks x 1024 threads (16 waves, 4/SIMD,
// 128-VGPR clean -- round-4 lesson: >128 dwords/thread pays AGPR/scratch tax).
// Thread (hd = tid>>2, q = tid&3) owns K-quarter q of all 4 gates of row hd:
//   i/f/g quarters in regs (96 dw), o quarter streamed from LDS (128 KB,
//   XOR-swizzled, conflict-free).
// Quarter partials reduced with 2 quad __shfl_xor (no LDS, no extra barrier).
// hs double-buffered (q-padded swizzle) -> ONE barrier per step.
// ---------------------------------------------------------------------------
__global__ __attribute__((amdgpu_flat_work_group_size(1024, 1024)))
void lstm_kernel(
    const ushort* __restrict__ wpk, const ushort* __restrict__ gx2,
    ushort* __restrict__ hbuf,     // [B][TCc][H] f16
    float* __restrict__ state,     // [2][64][256]: c then h
    int TCc, int first) {

    __shared__ __align__(16) ushort wg4[256 * 256];  // o-gate rows, 128 KB
    __shared__ __align__(16) ushort hs[2][288];      // h dbuf, q-padded swizzle

    const int tid = threadIdx.x;
    const int q   = tid & 3;        // K-quarter: k in [q*64, q*64+64)
    const int hd  = tid >> 2;       // owned h-dim
    const int hm  = hd & 31;
    const int b   = blockIdx.x;

    // --- preload i/f/g K-quarters into registers (16B/lane, coalesced) ---
    uint32_t wi[32], wf[32], wg[32];
#pragma unroll
    for (int k = 0; k < 8; ++k) {
        uint4 v = *(const uint4*)(wpk + (size_t)(0 * 32 + q * 8 + k) * 2048 + hd * 8);
        wi[k * 4 + 0] = v.x; wi[k * 4 + 1] = v.y; wi[k * 4 + 2] = v.z; wi[k * 4 + 3] = v.w;
    }
#pragma unroll
    for (int k = 0; k < 8; ++k) {
        uint4 v = *(const uint4*)(wpk + (size_t)(1 * 32 + q * 8 + k) * 2048 + hd * 8);
        wf[k * 4 + 0] = v.x; wf[k * 4 + 1] = v.y; wf[k * 4 + 2] = v.z; wf[k * 4 + 3] = v.w;
    }
#pragma unroll
    for (int k = 0; k < 8; ++k) {
        uint4 v = *(const uint4*)(wpk + (size_t)(2 * 32 + q * 8 + k) * 2048 + hd * 8);
        wg[k * 4 + 0] = v.x; wg[k * 4 + 1] = v.y; wg[k * 4 + 2] = v.z; wg[k * 4 + 3] = v.w;
    }
    // --- o-gate K-quarter -> LDS [hd][u], u = kc ^ (hd&31) (proven 0-conflict) ---
#pragma unroll
    for (int k = 0; k < 8; ++k) {
        uint4 v = *(const uint4*)(wpk + (size_t)(3 * 32 + q * 8 + k) * 2048 + hd * 8);
        int u = (q * 8 + k) ^ hm;
        *(uint4*)(wg4 + hd * 256 + u * 8) = v;
    }

    float c = 0.f, h = 0.f;
    if (!first) {
        c = state[b * H_ + hd];
        h = state[B_ * H_ + b * H_ + hd];
    }
    if (q == 0) {
        // value for h-dim hd -> chunk kc=hd>>3 at padded slot kc+(kc>>3)
        int sw = ((hd >> 3) + (hd >> 6)) * 8 + (hd & 7);
        hs[0][sw] = f2h(h);
    }
    __syncthreads();

    const ushort* gxb = gx2 + (size_t)b * TCc * G4_;
    ushort* hb = hbuf + (size_t)b * TCc * H_;

    ushort4 cg = *(const ushort4*)(gxb + (size_t)0 * G4_ + hd * 4);

    for (int tl = 0; tl < TCc; ++tl) {
        // prefetch next step's gates (hidden under the dot loop)
        const int tn = (tl + 1 < TCc) ? tl + 1 : tl;
        ushort4 ng = *(const ushort4*)(gxb + (size_t)tn * G4_ + hd * 4);

        const ushort* hsr = hs[tl & 1];
        float ai = 0.f, af = 0.f, agv = 0.f, ao = 0.f;

#pragma unroll
        for (int k = 0; k < 8; ++k) {
            // h chunk q*8+k at padded slot (q*9+k); 4 distinct addrs/wave,
            // distinct bank-quads (q+k mod 8) -> conflict-free broadcast
            uint4 hq = *(const uint4*)(hsr + (q * 9 + k) * 8);
            int u = (q * 8 + k) ^ hm;
            uint4 wo = *(const uint4*)(wg4 + hd * 256 + u * 8);
            ai  = fdot2(wi[k * 4 + 0], hq.x, ai);
            ai  = fdot2(wi[k * 4 + 1], hq.y, ai);
            ai  = fdot2(wi[k * 4 + 2], hq.z, ai);
            ai  = fdot2(wi[k * 4 + 3], hq.w, ai);
            af  = fdot2(wf[k * 4 + 0], hq.x, af);
            af  = fdot2(wf[k * 4 + 1], hq.y, af);
            af  = fdot2(wf[k * 4 + 2], hq.z, af);
            af  = fdot2(wf[k * 4 + 3], hq.w, af);
            agv = fdot2(wg[k * 4 + 0], hq.x, agv);
            agv = fdot2(wg[k * 4 + 1], hq.y, agv);
            agv = fdot2(wg[k * 4 + 2], hq.z, agv);
            agv = fdot2(wg[k * 4 + 3], hq.w, agv);
            ao  = fdot2(wo.x, hq.x, ao);
            ao  = fdot2(wo.y, hq.y, ao);
            ao  = fdot2(wo.z, hq.z, ao);
            ao  = fdot2(wo.w, hq.w, ao);
        }

        // reduce the 4 K-quarter partials across the lane quad (DPP, no LDS)
        ai  += __shfl_xor(ai, 1);  ai  += __shfl_xor(ai, 2);
        af  += __shfl_xor(af, 1);  af  += __shfl_xor(af, 2);
        agv += __shfl_xor(agv, 1); agv += __shfl_xor(agv, 2);
        ao  += __shfl_xor(ao, 1);  ao  += __shfl_xor(ao, 2);

        ai += h2f(cg.x); af += h2f(cg.y); agv += h2f(cg.z); ao += h2f(cg.w);

        // elementwise cell update (all lanes, redundant but divergence-free)
        float si = __builtin_amdgcn_rcpf(1.f + __expf(-ai));
        float sf = __builtin_amdgcn_rcpf(1.f + __expf(-af));
        float so = __builtin_amdgcn_rcpf(1.f + __expf(-ao));
        float eg = __expf(2.f * agv);
        float tg = (eg - 1.f) * __builtin_amdgcn_rcpf(eg + 1.f);
        c = sf * c + si * tg;
        float ec = __expf(2.f * c);
        float tc = (ec - 1.f) * __builtin_amdgcn_rcpf(ec + 1.f);
        h = so * tc;

        if (q == 0) {
            ushort hh = f2h(h);
            int sw = ((hd >> 3) + (hd >> 6)) * 8 + (hd & 7);
            hs[(tl + 1) & 1][sw] = hh;       // write OTHER buffer: 1 barrier/step
            hb[(size_t)tl * H_ + hd] = hh;
        }
        __syncthreads();

        cg = ng;
    }

    if (q == 0) {
        state[b * H_ + hd]           = c;
        state[B_ * H_ + b * H_ + hd] = h;
    }
}

// ---------------------------------------------------------------------------
// out[b,t] = sum_hd h[b,t,hd] * Wo[hd] + bo.  h f16 rows, fully dense reads.
// ---------------------------------------------------------------------------
__global__ __launch_bounds__(256) void proj_kernel(
    const ushort* __restrict__ hbuf, const float* __restrict__ Wo,
    const float* __restrict__ bo, float* __restrict__ out, int t0, int TCc) {

    const int lane = threadIdx.x & 63;
    const int wid  = blockIdx.x * 4 + (threadIdx.x >> 6);
    const int nw   = gridDim.x * 4;
    const int rows = B_ * TCc;

    float4 w = *(const float4*)(Wo + lane * 4);
    const float bov = bo[0];

    for (int r = wid; r < rows; r += nw) {
        const ushort* hp = hbuf + (size_t)r * H_ + lane * 4;
        ushort4 u = *(const ushort4*)hp;
        float p = h2f(u.x) * w.x + h2f(u.y) * w.y + h2f(u.z) * w.z + h2f(u.w) * w.w;
#pragma unroll
        for (int m = 1; m < 64; m <<= 1) p += __shfl_xor(p, m, 64);
        if (lane == 0) {
            int b  = r / TCc;
            int tl = r - b * TCc;
            out[(size_t)b * T_ + t0 + tl] = p + bov;
        }
    }
}

// ---------------------------------------------------------------------------
extern "C" void kernel_launch(void* const* d_in, const int* in_sizes, int n_in,
                              void* d_out, int out_size, void* d_ws, size_t ws_size,
                              hipStream_t stream) {
    const float* x   = (const float*)d_in[0];
    const float* Wih = (const float*)d_in[1];
    const float* Whh = (const float*)d_in[2];
    const float* bih = (const float*)d_in[3];
    const float* bhh = (const float*)d_in[4];
    const float* Wo  = (const float*)d_in[5];
    const float* bo  = (const float*)d_in[6];
    float* out = (float*)d_out;

    char* ws = (char*)d_ws;
    ushort* wpk   = (ushort*)ws;                              // 512 KB
    float*  state = (float*)(ws + 512 * 1024);                // 128 KB
    char*   dyn   = ws + 640 * 1024;                          // gx2 + hbuf chunks

    size_t avail = (ws_size > 640 * 1024) ? ws_size - 640 * 1024 : 0;
    // per (b,t): gx2 row 2048 B + hbuf row 512 B
    long long tcmax = (long long)(avail / ((size_t)B_ * (G4_ + H_) * 2));
    // Cap chunks at 512 steps so gx2 (64MB) + hbuf (16MB) stay L3-resident.
    int TC = (tcmax > 512) ? 512 : (int)tcmax;
    TC &= ~63;               // multiple of 64
    if (TC < 64) TC = 64;    // minimum viable chunk

    repack_kernel<<<1024, 256, 0, stream>>>(Whh, wpk);

    for (int t0 = 0; t0 < T_; t0 += TC) {
        int TCc = (T_ - t0 < TC) ? (T_ - t0) : TC;
        ushort* gxb  = (ushort*)dyn;
        ushort* hbuf = (ushort*)(dyn + (size_t)B_ * TCc * G4_ * 2);
        dim3 g1((B_ * TCc) / 32, 4);
        gx_kernel<<<g1, 256, 0, stream>>>(x, Wih, bih, bhh, gxb, t0, TCc);
        lstm_kernel<<<B_, 1024, 0, stream>>>(wpk, gxb, hbuf, state, TCc, t0 == 0 ? 1 : 0);
        proj_kernel<<<256, 256, 0, stream>>>(hbuf, Wo, bo, out, t0, TCc);
    }
    (void)in_sizes; (void)n_in; (void)out_size;
}